// Round 2
// baseline (1252.066 us; speedup 1.0000x reference)
//
#include <hip/hip_runtime.h>
#include <stdint.h>

// HashGridEncoding fused with Linear(32->64), round 2.
// 4 threads per point: thread group g in {0,1,2,3} computes levels 4g..4g+3,
// writing its 8 enc floats to LDS. Then per-wave matvec (lane = out channel),
// non-temporal coalesced stores.
//
// Rationale (rocprof r1): latency-bound — VALUBusy 7.7%, occupancy 22%,
// FETCH 3.4GB at 45% "HBM" (mostly L3-served). Fix = 4x thread parallelism,
// shorter per-thread load chains, smaller LDS (36KB->8KB), nt stores.

constexpr uint32_t TSIZE = 1u << 19;
constexpr int RAW = 32;            // L*F
constexpr int ODIM = 64;
constexpr int PPB = 64;            // points per block

__device__ __forceinline__ uint32_t umin32(uint32_t a, uint32_t b) { return a < b ? a : b; }

__global__ __launch_bounds__(256, 6) void hashgrid_fused2(
    const float* __restrict__ x,
    const float* __restrict__ table,
    const float* __restrict__ W,
    const float* __restrict__ bias,
    float* __restrict__ out)
{
    __shared__ float encS[PPB * RAW];   // 8 KB

    const int tid = threadIdx.x;
    const int pl  = tid >> 2;           // local point 0..63
    const int g   = tid & 3;            // level group: levels 4g..4g+3
    const int p   = blockIdx.x * PPB + pl;

    const float xn0 = (x[3 * p + 0] + 1.0f) * 0.5f;
    const float xn1 = (x[3 * p + 1] + 1.0f) * 0.5f;
    const float xn2 = (x[3 * p + 2] + 1.0f) * 0.5f;

    float e[8];   // 4 levels x F=2

    if (g == 0) {
        // ---- dense levels 0..3 (res^3 <= T), compile-time constants ----
        static constexpr float dS[4] = {15.0f, 23.0f, 35.0f, 53.0f};
        static constexpr uint32_t dR[4] = {16, 24, 36, 54};
#pragma unroll
        for (int ll = 0; ll < 4; ++ll) {
            const float s = dS[ll];
            const uint32_t res = dR[ll];
            const float pa = fmaf(xn0, s, 0.5f);
            const float pb = fmaf(xn1, s, 0.5f);
            const float pc = fmaf(xn2, s, 0.5f);
            const float fa = floorf(pa), fb = floorf(pb), fc = floorf(pc);
            const float ra = pa - fa, rb = pb - fb, rc = pc - fc;
            const uint32_t ca = (uint32_t)fa, cb = (uint32_t)fb, cc = (uint32_t)fc;

            const uint32_t rm = res - 1u;
            const uint32_t rr = res * res;
            const uint32_t x0 = umin32(ca, rm);
            const uint32_t x1 = umin32(ca + 1u, rm);
            const uint32_t y0 = umin32(cb, rm) * res;
            const uint32_t y1 = umin32(cb + 1u, rm) * res;
            const uint32_t z0 = umin32(cc, rm) * rr;
            const uint32_t z1 = umin32(cc + 1u, rm) * rr;
            uint32_t idx[8];
            idx[0] = x0 + y0 + z0; idx[1] = x0 + y0 + z1;
            idx[2] = x0 + y1 + z0; idx[3] = x0 + y1 + z1;
            idx[4] = x1 + y0 + z0; idx[5] = x1 + y0 + z1;
            idx[6] = x1 + y1 + z0; idx[7] = x1 + y1 + z1;

            const float2* tl = reinterpret_cast<const float2*>(table) + (size_t)ll * TSIZE;
            float2 gv[8];
#pragma unroll
            for (int k = 0; k < 8; ++k) gv[k] = tl[idx[k]];

            const float wa0 = 1.0f - ra, wb0 = 1.0f - rb, wc0 = 1.0f - rc;
            float e0 = 0.0f, e1 = 0.0f;
#pragma unroll
            for (int k = 0; k < 8; ++k) {
                const float w = ((k & 4) ? ra : wa0) * ((k & 2) ? rb : wb0) * ((k & 1) ? rc : wc0);
                e0 = fmaf(w, gv[k].x, e0);
                e1 = fmaf(w, gv[k].y, e1);
            }
            e[2 * ll] = e0; e[2 * ll + 1] = e1;
        }
    } else {
        // ---- hashed levels 4g..4g+3; scales selected per group ----
        float s0, s1, s2, s3;
        if (g == 1)      { s0 = 80.0f;          s1 = 120.5f;          s2 = 181.25f;          s3 = 272.375f; }
        else if (g == 2) { s0 = 409.0625f;      s1 = 614.09375f;      s2 = 921.640625f;      s3 = 1382.9609375f; }
        else             { s0 = 2074.94140625f; s1 = 3112.912109375f; s2 = 4669.8681640625f; s3 = 7005.30224609375f; }
        const float sArr[4] = {s0, s1, s2, s3};
        const float2* tbase = reinterpret_cast<const float2*>(table) + (size_t)(4 * g) * TSIZE;

#pragma unroll
        for (int ll = 0; ll < 4; ++ll) {
            const float s = sArr[ll];
            const float pa = fmaf(xn0, s, 0.5f);
            const float pb = fmaf(xn1, s, 0.5f);
            const float pc = fmaf(xn2, s, 0.5f);
            const float fa = floorf(pa), fb = floorf(pb), fc = floorf(pc);
            const float ra = pa - fa, rb = pb - fb, rc = pc - fc;
            const uint32_t ca = (uint32_t)fa, cb = (uint32_t)fb, cc = (uint32_t)fc;

            const uint32_t hx0 = ca;
            const uint32_t hx1 = ca + 1u;
            const uint32_t hy0 = cb * 2654435761u;
            const uint32_t hy1 = hy0 + 2654435761u;
            const uint32_t hz0 = cc * 805459861u;
            const uint32_t hz1 = hz0 + 805459861u;
            uint32_t idx[8];
            idx[0] = (hx0 ^ hy0 ^ hz0) & (TSIZE - 1u);
            idx[1] = (hx0 ^ hy0 ^ hz1) & (TSIZE - 1u);
            idx[2] = (hx0 ^ hy1 ^ hz0) & (TSIZE - 1u);
            idx[3] = (hx0 ^ hy1 ^ hz1) & (TSIZE - 1u);
            idx[4] = (hx1 ^ hy0 ^ hz0) & (TSIZE - 1u);
            idx[5] = (hx1 ^ hy0 ^ hz1) & (TSIZE - 1u);
            idx[6] = (hx1 ^ hy1 ^ hz0) & (TSIZE - 1u);
            idx[7] = (hx1 ^ hy1 ^ hz1) & (TSIZE - 1u);

            const float2* tl = tbase + (size_t)ll * TSIZE;
            float2 gv[8];
#pragma unroll
            for (int k = 0; k < 8; ++k) gv[k] = tl[idx[k]];

            const float wa0 = 1.0f - ra, wb0 = 1.0f - rb, wc0 = 1.0f - rc;
            float e0 = 0.0f, e1 = 0.0f;
#pragma unroll
            for (int k = 0; k < 8; ++k) {
                const float w = ((k & 4) ? ra : wa0) * ((k & 2) ? rb : wb0) * ((k & 1) ? rc : wc0);
                e0 = fmaf(w, gv[k].x, e0);
                e1 = fmaf(w, gv[k].y, e1);
            }
            e[2 * ll] = e0; e[2 * ll + 1] = e1;
        }
    }

    // stage partial enc into LDS: point pl, features [8g, 8g+8)
    {
        float4* ev = reinterpret_cast<float4*>(e);
        float4* row = reinterpret_cast<float4*>(&encS[pl * RAW + g * 8]);
        row[0] = ev[0];
        row[1] = ev[1];
    }

    // per-lane W row (channel = lane) — issued before barrier to overlap latency
    const int lane = tid & 63;
    const int wv   = tid >> 6;
    float Wr[RAW];
    {
        const float4* W4 = reinterpret_cast<const float4*>(W);
        float4* wr4 = reinterpret_cast<float4*>(Wr);
#pragma unroll
        for (int k = 0; k < 8; ++k) wr4[k] = W4[lane * 8 + k];
    }
    const float bj = bias[lane];

    __syncthreads();

    // phase 2: wave wv handles points [wv*16, wv*16+16); lane = output channel.
    // LDS reads are full-wave broadcasts (conflict-free); stores are 256B coalesced.
    const size_t outBase = (size_t)blockIdx.x * PPB * ODIM;
#pragma unroll 4
    for (int i = 0; i < 16; ++i) {
        const int q = wv * 16 + i;
        const float4* er = reinterpret_cast<const float4*>(&encS[q * RAW]);
        float acc = bj;
#pragma unroll
        for (int k4 = 0; k4 < 8; ++k4) {
            const float4 ev = er[k4];
            acc = fmaf(ev.x, Wr[4 * k4 + 0], acc);
            acc = fmaf(ev.y, Wr[4 * k4 + 1], acc);
            acc = fmaf(ev.z, Wr[4 * k4 + 2], acc);
            acc = fmaf(ev.w, Wr[4 * k4 + 3], acc);
        }
        __builtin_nontemporal_store(acc, out + outBase + (size_t)q * ODIM + lane);
    }
}

extern "C" void kernel_launch(void* const* d_in, const int* in_sizes, int n_in,
                              void* d_out, int out_size, void* d_ws, size_t ws_size,
                              hipStream_t stream) {
    const float* x = (const float*)d_in[0];      // [B,N,3]
    const float* table = (const float*)d_in[1];  // [L,T,F]
    const float* W = (const float*)d_in[2];      // [64,32]
    const float* b = (const float*)d_in[3];      // [64]
    float* out = (float*)d_out;                  // [B,N,64]

    const int P = in_sizes[0] / 3;               // 1048576
    const int blocks = P / PPB;                  // 16384
    hipLaunchKernelGGL(hashgrid_fused2, dim3(blocks), dim3(256), 0, stream,
                       x, table, W, b, out);
}